// Round 3
// baseline (4795.522 us; speedup 1.0000x reference)
//
#include <hip/hip_runtime.h>
#include <hip/hip_bf16.h>

#define S_DIM 128
#define B_DIM 4
#define L_DIM (S_DIM * S_DIM)   // 16384 per batch

typedef __bf16 bf16x8 __attribute__((ext_vector_type(8)));
typedef float f32x4 __attribute__((ext_vector_type(4)));

__device__ __forceinline__ float b2f(unsigned short u) {
    union { unsigned int i; float f; } v;
    v.i = ((unsigned int)u) << 16;
    return v.f;
}
__device__ __forceinline__ unsigned short f2b(float f) {
    union { float f; unsigned int i; } v;
    v.f = f;
    unsigned int x = v.i;
    return (unsigned short)((x + 0x7FFFu + ((x >> 16) & 1u)) >> 16);
}
// dtype-flag-aware scalar load of external input element i
__device__ __forceinline__ float ldx(const void* p, size_t i, int f32) {
    return f32 ? ((const float*)p)[i] : b2f(((const unsigned short*)p)[i]);
}

// ---------------------------------------------------------------------------
// Input dtype sniffer. Under f32-truth, even u16s of x are random mantissa
// bits: ~43% have exponent field >= 0x91 (|v| >= 2^18 — impossible for the
// reference's N(0,1) data). Under bf16-truth: zero such elements.
// ---------------------------------------------------------------------------
__global__ __launch_bounds__(256) void sniff_dtype(const unsigned short* __restrict__ x,
                                                   int* __restrict__ flag) {
    __shared__ int cnt;
    if (threadIdx.x == 0) cnt = 0;
    __syncthreads();
    int c = 0;
    for (int i = threadIdx.x; i < 32768; i += 256) {
        unsigned int e = (x[i] >> 7) & 0xFFu;
        if (e >= 0x91u) c++;
    }
    atomicAdd(&cnt, c);
    __syncthreads();
    if (threadIdx.x == 0) flag[0] = (cnt > 64) ? 1 : 0;
}

// ---------------------------------------------------------------------------
// Transpose external weight src[R][C] -> bf16 dst[C][R]
// ---------------------------------------------------------------------------
__global__ void transpose_any(const void* __restrict__ src,
                              unsigned short* __restrict__ dst, int R, int C,
                              const int* __restrict__ flag) {
    const int f = flag[0];
    int idx = blockIdx.x * 256 + threadIdx.x;
    if (idx >= R * C) return;
    int r = idx / C, c = idx - r * C;
    dst[c * R + r] = f2b(ldx(src, idx, f));
}

// ---------------------------------------------------------------------------
// Implicit filter MLP -> hx/hy [s][d] f32 (includes decay)
// ---------------------------------------------------------------------------
__global__ __launch_bounds__(128) void filter_mlp(
    const void* __restrict__ freq,
    const void* __restrict__ w0, const void* __restrict__ b0,
    const void* __restrict__ w1, const void* __restrict__ b1,
    const void* __restrict__ w2, const void* __restrict__ b2,
    const void* __restrict__ w3,
    float* __restrict__ out, const int* __restrict__ flag)
{
    const int f32f = flag[0];
    const int s = threadIdx.x;
    const float t = (float)s / (float)(S_DIM - 1);
    const float ang = 1e-4f * 2.0f * 3.14159265358979323846f * ((float)s / (float)S_DIM);
    const float z0 = t, z1 = cosf(ang), z2 = -sinf(ang);

    float h[64], g[64];
    for (int f = 0; f < 64; f++) {
        float a = z0 * ldx(w0, 0 * 64 + f, f32f) + z1 * ldx(w0, 1 * 64 + f, f32f) +
                  z2 * ldx(w0, 2 * 64 + f, f32f) + ldx(b0, f, f32f);
        h[f] = sinf(ldx(freq, f, f32f) * a);
    }
    for (int f = 0; f < 64; f++) {
        float a = ldx(b1, f, f32f);
        for (int e = 0; e < 64; e++) a += h[e] * ldx(w1, e * 64 + f, f32f);
        g[f] = sinf(ldx(freq, f, f32f) * a);
    }
    for (int f = 0; f < 64; f++) {
        float a = ldx(b2, f, f32f);
        for (int e = 0; e < 64; e++) a += g[e] * ldx(w2, e * 64 + f, f32f);
        h[f] = sinf(ldx(freq, f, f32f) * a);
    }
    const float min_d = -3.0701134573253943f;   // ln(0.01)/1.5
    const float max_d = -15.350567286626971f;   // ln(0.01)/0.3
    for (int d = 0; d < 256; d++) {
        float a = 0.f;
        for (int e = 0; e < 64; e++) a += h[e] * ldx(w3, e * 256 + d, f32f);
        float delta = min_d + (max_d - min_d) * ((float)d / 255.0f);
        float dec = expf(-t * fabsf(delta));
        out[s * 256 + d] = a * dec;
    }
}

// ---------------------------------------------------------------------------
// GEMM: C[M][N] = A[M][K] * BT[N][K]^T + bias[N].
// A may be external (dtype per flag) or internal bf16; C may be external
// (f32 under f32-truth) or internal bf16. BT always internal bf16.
// 128x128 tile, 4 waves 2x2, 4x4 MFMA 16x16x32 frags per wave.
// ---------------------------------------------------------------------------
__global__ __launch_bounds__(256) void gemm_bt(
    const void* __restrict__ A, size_t a_off, int a_ext,
    const unsigned short* __restrict__ BT,
    const void* __restrict__ bias, int bias_ext,
    void* __restrict__ C, size_t c_off, int c_ext,
    int M, int N, int K, const int* __restrict__ flag)
{
    __shared__ unsigned short As[128 * 40];  // pad 32 -> 40 (stride 80B)
    __shared__ unsigned short Bs[128 * 40];

    const int f    = flag[0];
    const int a_f32 = a_ext && f;
    const int b_f32 = bias_ext && f;
    const int c_f32 = c_ext && f;

    const int tid  = threadIdx.x;
    const int m0   = blockIdx.x * 128;
    const int n0   = blockIdx.y * 128;
    const int wid  = tid >> 6;
    const int lane = tid & 63;
    const int lrow = lane & 15;
    const int quad = lane >> 4;
    const int wr   = wid >> 1, wc = wid & 1;

    f32x4 acc[4][4];
#pragma unroll
    for (int a = 0; a < 4; a++)
#pragma unroll
        for (int b = 0; b < 4; b++)
#pragma unroll
            for (int r = 0; r < 4; r++) acc[a][b][r] = 0.0f;

    for (int kc = 0; kc < K; kc += 32) {
#pragma unroll
        for (int h = 0; h < 2; h++) {
            int c    = tid + h * 256;
            int row  = c >> 2;
            int col8 = (c & 3) * 8;
            size_t aidx = a_off + (size_t)(m0 + row) * K + kc + col8;
            if (a_f32) {
                const float4* ga = (const float4*)((const float*)A + aidx);
                float4 p0 = ga[0], p1 = ga[1];
                uint4 w;
                w.x = (unsigned int)f2b(p0.x) | ((unsigned int)f2b(p0.y) << 16);
                w.y = (unsigned int)f2b(p0.z) | ((unsigned int)f2b(p0.w) << 16);
                w.z = (unsigned int)f2b(p1.x) | ((unsigned int)f2b(p1.y) << 16);
                w.w = (unsigned int)f2b(p1.z) | ((unsigned int)f2b(p1.w) << 16);
                *(uint4*)(&As[row * 40 + col8]) = w;
            } else {
                *(uint4*)(&As[row * 40 + col8]) =
                    *(const uint4*)((const unsigned short*)A + aidx);
            }
            *(uint4*)(&Bs[row * 40 + col8]) =
                *(const uint4*)(BT + (size_t)(n0 + row) * K + kc + col8);
        }
        __syncthreads();

        bf16x8 af[4], bfr[4];
#pragma unroll
        for (int fm = 0; fm < 4; fm++)
            af[fm] = *(const bf16x8*)(&As[(wr * 64 + fm * 16 + lrow) * 40 + quad * 8]);
#pragma unroll
        for (int fn = 0; fn < 4; fn++)
            bfr[fn] = *(const bf16x8*)(&Bs[(wc * 64 + fn * 16 + lrow) * 40 + quad * 8]);
#pragma unroll
        for (int fm = 0; fm < 4; fm++)
#pragma unroll
            for (int fn = 0; fn < 4; fn++)
                acc[fm][fn] = __builtin_amdgcn_mfma_f32_16x16x32_bf16(
                    af[fm], bfr[fn], acc[fm][fn], 0, 0, 0);
        __syncthreads();
    }

#pragma unroll
    for (int fm = 0; fm < 4; fm++) {
#pragma unroll
        for (int fn = 0; fn < 4; fn++) {
            int gcol = n0 + wc * 64 + fn * 16 + lrow;
            float bv = ldx(bias, gcol, b_f32);
#pragma unroll
            for (int r = 0; r < 4; r++) {
                int grow = m0 + wr * 64 + fm * 16 + quad * 4 + r;
                size_t cidx = c_off + (size_t)grow * N + gcol;
                float val = acc[fm][fn][r] + bv;
                if (c_f32) ((float*)C)[cidx] = val;
                else       ((unsigned short*)C)[cidx] = f2b(val);
            }
        }
    }
}

// ---------------------------------------------------------------------------
// Depthwise 3x3 conv (taps -2,-1,0 both dims) + gate w = v*x1. ONE batch.
// ---------------------------------------------------------------------------
__global__ __launch_bounds__(256) void conv3_gate(
    const unsigned short* __restrict__ U,    // [L][768] internal bf16
    const void* __restrict__ sfw,            // [768][3][3] external
    const void* __restrict__ sfb,            // [768] external
    unsigned short* __restrict__ Wb,         // [L][256]  (v*x1)
    unsigned short* __restrict__ X0,         // [L][256]
    const int* __restrict__ flag)
{
    const int f32f = flag[0];
    const int i   = blockIdx.x;
    const int tid = threadIdx.x;

    float wgt[3][3][3], bias[3];
#pragma unroll
    for (int cc = 0; cc < 3; cc++) {
        int ch = cc * 256 + tid;
        bias[cc] = ldx(sfb, ch, f32f);
#pragma unroll
        for (int ki = 0; ki < 3; ki++)
#pragma unroll
            for (int kj = 0; kj < 3; kj++)
                wgt[cc][ki][kj] = ldx(sfw, ch * 9 + ki * 3 + kj, f32f);
    }

    float colA[3][3], colB[3][3];
#pragma unroll
    for (int cc = 0; cc < 3; cc++)
#pragma unroll
        for (int ki = 0; ki < 3; ki++) { colA[cc][ki] = 0.f; colB[cc][ki] = 0.f; }

    for (int j = 0; j < S_DIM; j++) {
        float cur[3][3];
#pragma unroll
        for (int ki = 0; ki < 3; ki++) {
            int row = i + ki - 2;
            bool ok = (row >= 0);
#pragma unroll
            for (int cc = 0; cc < 3; cc++)
                cur[cc][ki] = ok ? b2f(U[(size_t)(row * S_DIM + j) * 768 + cc * 256 + tid])
                                 : 0.f;
        }
        float o[3];
#pragma unroll
        for (int cc = 0; cc < 3; cc++) {
            float a = bias[cc];
#pragma unroll
            for (int ki = 0; ki < 3; ki++)
                a += wgt[cc][ki][0] * colA[cc][ki] + wgt[cc][ki][1] * colB[cc][ki] +
                     wgt[cc][ki][2] * cur[cc][ki];
            o[cc] = a;
        }
#pragma unroll
        for (int cc = 0; cc < 3; cc++)
#pragma unroll
            for (int ki = 0; ki < 3; ki++) { colA[cc][ki] = colB[cc][ki]; colB[cc][ki] = cur[cc][ki]; }

        size_t oidx = (size_t)(i * S_DIM + j) * 256 + tid;
        X0[oidx] = f2b(o[0]);
        Wb[oidx] = f2b(o[2] * o[1]);  // v * x1
    }
}

// ---------------------------------------------------------------------------
// Causal conv along j: A[i,j,d] = sum_{q<=j} hy[q,d]*w[i,j-q,d].  ONE batch.
// ---------------------------------------------------------------------------
__global__ __launch_bounds__(256) void conv_j(
    const unsigned short* __restrict__ Wb,   // [L][256]
    const float* __restrict__ hy,            // [S][256]
    unsigned short* __restrict__ Aout)       // [L][256]
{
    __shared__ unsigned short wl[S_DIM * 256];  // 64 KB, [j][d]
    const int i = blockIdx.x;
    const int tid = threadIdx.x;
    const size_t sbase = (size_t)(i * S_DIM) * 256;

    const uint4* gsrc = (const uint4*)(Wb + sbase);
    for (int c = tid; c < 4096; c += 256) ((uint4*)wl)[c] = gsrc[c];
    __syncthreads();

    const int d = tid;
    for (int jt = 0; jt < 8; jt++) {
        const int j0 = jt * 16;
        float acc[16];
#pragma unroll
        for (int jj = 0; jj < 16; jj++) acc[jj] = 0.f;

        float Wn[19];
#pragma unroll
        for (int t = 0; t < 19; t++) {
            int r = j0 - 3 + t;
            Wn[t] = (r >= 0) ? b2f(wl[r * 256 + d]) : 0.f;
        }
        const int qmax = j0 + 15;
        for (int q0 = 0; q0 <= qmax; q0 += 4) {
            float hv[4];
#pragma unroll
            for (int idx = 0; idx < 4; idx++) hv[idx] = hy[(q0 + idx) * 256 + d];
#pragma unroll
            for (int idx = 0; idx < 4; idx++)
#pragma unroll
                for (int jj = 0; jj < 16; jj++)
                    acc[jj] += hv[idx] * Wn[jj + 3 - idx];
            if (q0 + 4 <= qmax) {
#pragma unroll
                for (int t = 18; t >= 4; t--) Wn[t] = Wn[t - 4];
#pragma unroll
                for (int t = 0; t < 4; t++) {
                    int r = j0 - q0 - 7 + t;
                    Wn[t] = (r >= 0) ? b2f(wl[r * 256 + d]) : 0.f;
                }
            }
        }
#pragma unroll
        for (int jj = 0; jj < 16; jj++)
            Aout[sbase + (size_t)(j0 + jj) * 256 + d] = f2b(acc[jj]);
    }
}

// ---------------------------------------------------------------------------
// Causal conv along i + epilogue: y = conv/256 + w*fbias, out = y*x0. ONE batch.
// ---------------------------------------------------------------------------
__global__ __launch_bounds__(256) void conv_i(
    const unsigned short* __restrict__ Ain,   // [L][256]
    const float* __restrict__ hx,             // [S][256]
    const unsigned short* __restrict__ Wb,    // [L][256]
    const unsigned short* __restrict__ X0,    // [L][256]
    const void* __restrict__ fbias,           // [256] external
    unsigned short* __restrict__ Gout,        // [L][256]
    const int* __restrict__ flag)
{
    __shared__ unsigned short al[S_DIM * 256];  // [i][d]
    const int f32f = flag[0];
    const int j = blockIdx.x;
    const int tid = threadIdx.x;

    for (int c = tid; c < 4096; c += 256) {
        int row = c >> 5;
        int off = c & 31;
        const uint4* gsrc = (const uint4*)(Ain + (size_t)(row * S_DIM + j) * 256) + off;
        ((uint4*)al)[c] = *gsrc;
    }
    __syncthreads();

    const int d = tid;
    const float fb = ldx(fbias, d, f32f);
    for (int it = 0; it < 8; it++) {
        const int i0 = it * 16;
        float acc[16];
#pragma unroll
        for (int ii = 0; ii < 16; ii++) acc[ii] = 0.f;

        float Wn[19];
#pragma unroll
        for (int t = 0; t < 19; t++) {
            int r = i0 - 3 + t;
            Wn[t] = (r >= 0) ? b2f(al[r * 256 + d]) : 0.f;
        }
        const int qmax = i0 + 15;
        for (int q0 = 0; q0 <= qmax; q0 += 4) {
            float hv[4];
#pragma unroll
            for (int idx = 0; idx < 4; idx++) hv[idx] = hx[(q0 + idx) * 256 + d];
#pragma unroll
            for (int idx = 0; idx < 4; idx++)
#pragma unroll
                for (int ii = 0; ii < 16; ii++)
                    acc[ii] += hv[idx] * Wn[ii + 3 - idx];
            if (q0 + 4 <= qmax) {
#pragma unroll
                for (int t = 18; t >= 4; t--) Wn[t] = Wn[t - 4];
#pragma unroll
                for (int t = 0; t < 4; t++) {
                    int r = i0 - q0 - 7 + t;
                    Wn[t] = (r >= 0) ? b2f(al[r * 256 + d]) : 0.f;
                }
            }
        }
#pragma unroll
        for (int ii = 0; ii < 16; ii++) {
            int i = i0 + ii;
            size_t idx = (size_t)(i * S_DIM + j) * 256 + d;
            float wv  = b2f(Wb[idx]);
            float x0v = b2f(X0[idx]);
            float y = acc[ii] * (1.0f / 256.0f) + wv * fb;
            Gout[idx] = f2b(y * x0v);
        }
    }
}

// ---------------------------------------------------------------------------
extern "C" void kernel_launch(void* const* d_in, const int* in_sizes, int n_in,
                              void* d_out, int out_size, void* d_ws, size_t ws_size,
                              hipStream_t stream)
{
    const void* x     = d_in[0];
    const void* in_w  = d_in[1];
    const void* in_b  = d_in[2];
    const void* out_w = d_in[3];
    const void* out_b_= d_in[4];
    const void* sf_w  = d_in[5];
    const void* sf_b  = d_in[6];
    const void* freq  = d_in[7];
    const void* xw0 = d_in[8];  const void* xb0 = d_in[9];
    const void* xw1 = d_in[10]; const void* xb1 = d_in[11];
    const void* xw2 = d_in[12]; const void* xb2 = d_in[13];
    const void* xw3 = d_in[14];
    const void* yw0 = d_in[15]; const void* yb0 = d_in[16];
    const void* yw1 = d_in[17]; const void* yb1 = d_in[18];
    const void* yw2 = d_in[19]; const void* yb2 = d_in[20];
    const void* yw3 = d_in[21];
    const void* fbias = d_in[22];

    // Workspace layout (~42.7 MB). A_b and G_b overlay dead parts of u_b.
    char* ws = (char*)d_ws;
    unsigned short* u_b  = (unsigned short*)(ws + 0);          // 25165824 B
    unsigned short* A_b  = (unsigned short*)(ws + 0);          //  8388608 B (alias, u dead)
    unsigned short* G_b  = (unsigned short*)(ws + 8388608);    //  8388608 B (alias, u dead)
    unsigned short* Wb_b = (unsigned short*)(ws + 25165824);   //  8388608 B
    unsigned short* X0_b = (unsigned short*)(ws + 33554432);   //  8388608 B
    float* hx            = (float*)(ws + 41943040);            //   131072 B
    float* hy            = (float*)(ws + 42074112);            //   131072 B
    unsigned short* tin  = (unsigned short*)(ws + 42205184);   //   393216 B
    unsigned short* tout = (unsigned short*)(ws + 42598400);   //   131072 B
    int* flag            = (int*)(ws + 42729472);              //       16 B
    // end: 42729488 bytes

    sniff_dtype<<<1, 256, 0, stream>>>((const unsigned short*)x, flag);
    transpose_any<<<dim3((256 * 768 + 255) / 256), 256, 0, stream>>>(in_w, tin, 256, 768, flag);
    transpose_any<<<dim3((256 * 256 + 255) / 256), 256, 0, stream>>>(out_w, tout, 256, 256, flag);
    filter_mlp<<<1, 128, 0, stream>>>(freq, xw0, xb0, xw1, xb1, xw2, xb2, xw3, hx, flag);
    filter_mlp<<<1, 128, 0, stream>>>(freq, yw0, yb0, yw1, yb1, yw2, yb2, yw3, hy, flag);

    for (int b = 0; b < B_DIM; b++) {
        size_t xoff = (size_t)b * L_DIM * 256;

        gemm_bt<<<dim3(128, 6), 256, 0, stream>>>(
            x, xoff, /*a_ext=*/1, tin, in_b, /*bias_ext=*/1,
            u_b, 0, /*c_ext=*/0, L_DIM, 768, 256, flag);
        conv3_gate<<<dim3(S_DIM), 256, 0, stream>>>(u_b, sf_w, sf_b, Wb_b, X0_b, flag);
        conv_j<<<dim3(S_DIM), 256, 0, stream>>>(Wb_b, hy, A_b);
        conv_i<<<dim3(S_DIM), 256, 0, stream>>>(A_b, hx, Wb_b, X0_b, fbias, G_b, flag);
        gemm_bt<<<dim3(128, 2), 256, 0, stream>>>(
            G_b, 0, /*a_ext=*/0, tout, out_b_, /*bias_ext=*/1,
            d_out, xoff, /*c_ext=*/1, L_DIM, 256, 256, flag);
    }
}

// Round 4
// 920.099 us; speedup vs baseline: 5.2120x; 5.2120x over previous
//
#include <hip/hip_runtime.h>
#include <hip/hip_bf16.h>

#define S_DIM 128
#define B_DIM 4
#define L_DIM (S_DIM * S_DIM)   // 16384 per batch

typedef __bf16 bf16x8 __attribute__((ext_vector_type(8)));
typedef float f32x4 __attribute__((ext_vector_type(4)));

__device__ __forceinline__ float b2f(unsigned short u) {
    union { unsigned int i; float f; } v;
    v.i = ((unsigned int)u) << 16;
    return v.f;
}
__device__ __forceinline__ unsigned short f2b(float f) {
    union { float f; unsigned int i; } v;
    v.f = f;
    unsigned int x = v.i;
    return (unsigned short)((x + 0x7FFFu + ((x >> 16) & 1u)) >> 16);
}
// dtype-flag-aware scalar load of external input element i
__device__ __forceinline__ float ldx(const void* p, size_t i, int f32) {
    return f32 ? ((const float*)p)[i] : b2f(((const unsigned short*)p)[i]);
}

// ---------------------------------------------------------------------------
// Input dtype sniffer (f32 vs bf16 external inputs).
// ---------------------------------------------------------------------------
__global__ __launch_bounds__(256) void sniff_dtype(const unsigned short* __restrict__ x,
                                                   int* __restrict__ flag) {
    __shared__ int cnt;
    if (threadIdx.x == 0) cnt = 0;
    __syncthreads();
    int c = 0;
    for (int i = threadIdx.x; i < 32768; i += 256) {
        unsigned int e = (x[i] >> 7) & 0xFFu;
        if (e >= 0x91u) c++;
    }
    atomicAdd(&cnt, c);
    __syncthreads();
    if (threadIdx.x == 0) flag[0] = (cnt > 64) ? 1 : 0;
}

// ---------------------------------------------------------------------------
// Transpose external weight src[R][C] -> bf16 dst[C][R]
// ---------------------------------------------------------------------------
__global__ void transpose_any(const void* __restrict__ src,
                              unsigned short* __restrict__ dst, int R, int C,
                              const int* __restrict__ flag) {
    const int f = flag[0];
    int idx = blockIdx.x * 256 + threadIdx.x;
    if (idx >= R * C) return;
    int r = idx / C, c = idx - r * C;
    dst[c * R + r] = f2b(ldx(src, idx, f));
}

// ---------------------------------------------------------------------------
// Implicit filter MLP, PARALLEL: one block per s (grid 128, 256 threads).
// Layers 0-2 on threads 0..63 with LDS broadcast; w3 stage coalesced over
// all 256 threads. out [s][d] f32 (includes decay).
// ---------------------------------------------------------------------------
__global__ __launch_bounds__(256) void filter_mlp(
    const void* __restrict__ freq,
    const void* __restrict__ w0, const void* __restrict__ b0,
    const void* __restrict__ w1, const void* __restrict__ b1,
    const void* __restrict__ w2, const void* __restrict__ b2,
    const void* __restrict__ w3,
    float* __restrict__ out, const int* __restrict__ flag)
{
    __shared__ float hs[64], gs[64];
    const int f32f = flag[0];
    const int s   = blockIdx.x;
    const int tid = threadIdx.x;
    const float t = (float)s / (float)(S_DIM - 1);
    const float ang = 1e-4f * 2.0f * 3.14159265358979323846f * ((float)s / (float)S_DIM);
    const float z0 = t, z1 = cosf(ang), z2 = -sinf(ang);

    if (tid < 64) {
        float fr = ldx(freq, tid, f32f);
        float a = z0 * ldx(w0, 0 * 64 + tid, f32f) + z1 * ldx(w0, 1 * 64 + tid, f32f) +
                  z2 * ldx(w0, 2 * 64 + tid, f32f) + ldx(b0, tid, f32f);
        hs[tid] = sinf(fr * a);
    }
    __syncthreads();
    if (tid < 64) {
        float fr = ldx(freq, tid, f32f);
        float a = ldx(b1, tid, f32f);
        for (int e = 0; e < 64; e++) a += hs[e] * ldx(w1, e * 64 + tid, f32f);
        gs[tid] = sinf(fr * a);
    }
    __syncthreads();
    if (tid < 64) {
        float fr = ldx(freq, tid, f32f);
        float a = ldx(b2, tid, f32f);
        for (int e = 0; e < 64; e++) a += gs[e] * ldx(w2, e * 64 + tid, f32f);
        hs[tid] = sinf(fr * a);
    }
    __syncthreads();
    {
        const float min_d = -3.0701134573253943f;   // ln(0.01)/1.5
        const float max_d = -15.350567286626971f;   // ln(0.01)/0.3
        float a = 0.f;
        for (int e = 0; e < 64; e++) a += hs[e] * ldx(w3, e * 256 + tid, f32f);
        float delta = min_d + (max_d - min_d) * ((float)tid / 255.0f);
        float dec = expf(-t * fabsf(delta));
        out[s * 256 + tid] = a * dec;
    }
}

// ---------------------------------------------------------------------------
// GEMM: C[M][N] = A[M][K] * BT[N][K]^T + bias[N].  (layouts/flags as R3)
// ---------------------------------------------------------------------------
__global__ __launch_bounds__(256) void gemm_bt(
    const void* __restrict__ A, size_t a_off, int a_ext,
    const unsigned short* __restrict__ BT,
    const void* __restrict__ bias, int bias_ext,
    void* __restrict__ C, size_t c_off, int c_ext,
    int M, int N, int K, const int* __restrict__ flag)
{
    __shared__ unsigned short As[128 * 40];  // pad 32 -> 40 (stride 80B)
    __shared__ unsigned short Bs[128 * 40];

    const int f    = flag[0];
    const int a_f32 = a_ext && f;
    const int b_f32 = bias_ext && f;
    const int c_f32 = c_ext && f;

    const int tid  = threadIdx.x;
    const int m0   = blockIdx.x * 128;
    const int n0   = blockIdx.y * 128;
    const int wid  = tid >> 6;
    const int lane = tid & 63;
    const int lrow = lane & 15;
    const int quad = lane >> 4;
    const int wr   = wid >> 1, wc = wid & 1;

    f32x4 acc[4][4];
#pragma unroll
    for (int a = 0; a < 4; a++)
#pragma unroll
        for (int b = 0; b < 4; b++)
#pragma unroll
            for (int r = 0; r < 4; r++) acc[a][b][r] = 0.0f;

    for (int kc = 0; kc < K; kc += 32) {
#pragma unroll
        for (int h = 0; h < 2; h++) {
            int c    = tid + h * 256;
            int row  = c >> 2;
            int col8 = (c & 3) * 8;
            size_t aidx = a_off + (size_t)(m0 + row) * K + kc + col8;
            if (a_f32) {
                const float4* ga = (const float4*)((const float*)A + aidx);
                float4 p0 = ga[0], p1 = ga[1];
                uint4 w;
                w.x = (unsigned int)f2b(p0.x) | ((unsigned int)f2b(p0.y) << 16);
                w.y = (unsigned int)f2b(p0.z) | ((unsigned int)f2b(p0.w) << 16);
                w.z = (unsigned int)f2b(p1.x) | ((unsigned int)f2b(p1.y) << 16);
                w.w = (unsigned int)f2b(p1.z) | ((unsigned int)f2b(p1.w) << 16);
                *(uint4*)(&As[row * 40 + col8]) = w;
            } else {
                *(uint4*)(&As[row * 40 + col8]) =
                    *(const uint4*)((const unsigned short*)A + aidx);
            }
            *(uint4*)(&Bs[row * 40 + col8]) =
                *(const uint4*)(BT + (size_t)(n0 + row) * K + kc + col8);
        }
        __syncthreads();

        bf16x8 af[4], bfr[4];
#pragma unroll
        for (int fm = 0; fm < 4; fm++)
            af[fm] = *(const bf16x8*)(&As[(wr * 64 + fm * 16 + lrow) * 40 + quad * 8]);
#pragma unroll
        for (int fn = 0; fn < 4; fn++)
            bfr[fn] = *(const bf16x8*)(&Bs[(wc * 64 + fn * 16 + lrow) * 40 + quad * 8]);
#pragma unroll
        for (int fm = 0; fm < 4; fm++)
#pragma unroll
            for (int fn = 0; fn < 4; fn++)
                acc[fm][fn] = __builtin_amdgcn_mfma_f32_16x16x32_bf16(
                    af[fm], bfr[fn], acc[fm][fn], 0, 0, 0);
        __syncthreads();
    }

#pragma unroll
    for (int fm = 0; fm < 4; fm++) {
#pragma unroll
        for (int fn = 0; fn < 4; fn++) {
            int gcol = n0 + wc * 64 + fn * 16 + lrow;
            float bv = ldx(bias, gcol, b_f32);
#pragma unroll
            for (int r = 0; r < 4; r++) {
                int grow = m0 + wr * 64 + fm * 16 + quad * 4 + r;
                size_t cidx = c_off + (size_t)grow * N + gcol;
                float val = acc[fm][fn][r] + bv;
                if (c_f32) ((float*)C)[cidx] = val;
                else       ((unsigned short*)C)[cidx] = f2b(val);
            }
        }
    }
}

// ---------------------------------------------------------------------------
// Depthwise 3x3 conv (taps -2,-1,0 both dims) + gate w = v*x1. ONE batch.
// j-range split 4-way: block (i, js) handles j in [js*32, js*32+32) with a
// 2-column preamble to warm the sliding window. Grid (S, 4).
// ---------------------------------------------------------------------------
__global__ __launch_bounds__(256) void conv3_gate(
    const unsigned short* __restrict__ U,    // [L][768] internal bf16
    const void* __restrict__ sfw,            // [768][3][3] external
    const void* __restrict__ sfb,            // [768] external
    unsigned short* __restrict__ Wb,         // [L][256]  (v*x1)
    unsigned short* __restrict__ X0,         // [L][256]
    const int* __restrict__ flag)
{
    const int f32f = flag[0];
    const int i   = blockIdx.x;
    const int j0  = blockIdx.y * 32;
    const int tid = threadIdx.x;

    float wgt[3][3][3], bias[3];
#pragma unroll
    for (int cc = 0; cc < 3; cc++) {
        int ch = cc * 256 + tid;
        bias[cc] = ldx(sfb, ch, f32f);
#pragma unroll
        for (int ki = 0; ki < 3; ki++)
#pragma unroll
            for (int kj = 0; kj < 3; kj++)
                wgt[cc][ki][kj] = ldx(sfw, ch * 9 + ki * 3 + kj, f32f);
    }

    float colA[3][3], colB[3][3];
#pragma unroll
    for (int cc = 0; cc < 3; cc++)
#pragma unroll
        for (int ki = 0; ki < 3; ki++) { colA[cc][ki] = 0.f; colB[cc][ki] = 0.f; }

    for (int j = j0 - 2; j < j0 + 32; j++) {
        if (j < 0) continue;   // columns < 0 are zero (already in colA/colB)
        float cur[3][3];
#pragma unroll
        for (int ki = 0; ki < 3; ki++) {
            int row = i + ki - 2;
            bool ok = (row >= 0);
#pragma unroll
            for (int cc = 0; cc < 3; cc++)
                cur[cc][ki] = ok ? b2f(U[(size_t)(row * S_DIM + j) * 768 + cc * 256 + tid])
                                 : 0.f;
        }
        if (j >= j0) {
            float o[3];
#pragma unroll
            for (int cc = 0; cc < 3; cc++) {
                float a = bias[cc];
#pragma unroll
                for (int ki = 0; ki < 3; ki++)
                    a += wgt[cc][ki][0] * colA[cc][ki] + wgt[cc][ki][1] * colB[cc][ki] +
                         wgt[cc][ki][2] * cur[cc][ki];
                o[cc] = a;
            }
            size_t oidx = (size_t)(i * S_DIM + j) * 256 + tid;
            X0[oidx] = f2b(o[0]);
            Wb[oidx] = f2b(o[2] * o[1]);  // v * x1
        }
#pragma unroll
        for (int cc = 0; cc < 3; cc++)
#pragma unroll
            for (int ki = 0; ki < 3; ki++) { colA[cc][ki] = colB[cc][ki]; colB[cc][ki] = cur[cc][ki]; }
    }
}

// ---------------------------------------------------------------------------
// Causal conv along j: A[i,j,d] = sum_{q<=j} hy[q,d]*w[i,j-q,d].  ONE batch.
// Grid (S, 4): block h computes balanced tile pair {h, 7-h} (cost 144 each).
// ---------------------------------------------------------------------------
__global__ __launch_bounds__(256) void conv_j(
    const unsigned short* __restrict__ Wb,   // [L][256]
    const float* __restrict__ hy,            // [S][256]
    unsigned short* __restrict__ Aout)       // [L][256]
{
    __shared__ unsigned short wl[S_DIM * 256];  // 64 KB, [j][d]
    const int i = blockIdx.x;
    const int h = blockIdx.y;
    const int tid = threadIdx.x;
    const size_t sbase = (size_t)(i * S_DIM) * 256;

    const uint4* gsrc = (const uint4*)(Wb + sbase);
    for (int c = tid; c < 4096; c += 256) ((uint4*)wl)[c] = gsrc[c];
    __syncthreads();

    const int d = tid;
    for (int pick = 0; pick < 2; pick++) {
        const int jt = pick ? (7 - h) : h;
        const int j0 = jt * 16;
        float acc[16];
#pragma unroll
        for (int jj = 0; jj < 16; jj++) acc[jj] = 0.f;

        float Wn[19];
#pragma unroll
        for (int t = 0; t < 19; t++) {
            int r = j0 - 3 + t;
            Wn[t] = (r >= 0) ? b2f(wl[r * 256 + d]) : 0.f;
        }
        const int qmax = j0 + 15;
        for (int q0 = 0; q0 <= qmax; q0 += 4) {
            float hv[4];
#pragma unroll
            for (int idx = 0; idx < 4; idx++) hv[idx] = hy[(q0 + idx) * 256 + d];
#pragma unroll
            for (int idx = 0; idx < 4; idx++)
#pragma unroll
                for (int jj = 0; jj < 16; jj++)
                    acc[jj] += hv[idx] * Wn[jj + 3 - idx];
            if (q0 + 4 <= qmax) {
#pragma unroll
                for (int t = 18; t >= 4; t--) Wn[t] = Wn[t - 4];
#pragma unroll
                for (int t = 0; t < 4; t++) {
                    int r = j0 - q0 - 7 + t;
                    Wn[t] = (r >= 0) ? b2f(wl[r * 256 + d]) : 0.f;
                }
            }
        }
#pragma unroll
        for (int jj = 0; jj < 16; jj++)
            Aout[sbase + (size_t)(j0 + jj) * 256 + d] = f2b(acc[jj]);
    }
}

// ---------------------------------------------------------------------------
// Causal conv along i + epilogue: y = conv/256 + w*fbias, out = y*x0. ONE batch.
// Grid (S, 4): block h computes tile pair {h, 7-h}.
// ---------------------------------------------------------------------------
__global__ __launch_bounds__(256) void conv_i(
    const unsigned short* __restrict__ Ain,   // [L][256]
    const float* __restrict__ hx,             // [S][256]
    const unsigned short* __restrict__ Wb,    // [L][256]
    const unsigned short* __restrict__ X0,    // [L][256]
    const void* __restrict__ fbias,           // [256] external
    unsigned short* __restrict__ Gout,        // [L][256]
    const int* __restrict__ flag)
{
    __shared__ unsigned short al[S_DIM * 256];  // [i][d]
    const int f32f = flag[0];
    const int j = blockIdx.x;
    const int h = blockIdx.y;
    const int tid = threadIdx.x;

    for (int c = tid; c < 4096; c += 256) {
        int row = c >> 5;
        int off = c & 31;
        const uint4* gsrc = (const uint4*)(Ain + (size_t)(row * S_DIM + j) * 256) + off;
        ((uint4*)al)[c] = *gsrc;
    }
    __syncthreads();

    const int d = tid;
    const float fb = ldx(fbias, d, f32f);
    for (int pick = 0; pick < 2; pick++) {
        const int it = pick ? (7 - h) : h;
        const int i0 = it * 16;
        float acc[16];
#pragma unroll
        for (int ii = 0; ii < 16; ii++) acc[ii] = 0.f;

        float Wn[19];
#pragma unroll
        for (int t = 0; t < 19; t++) {
            int r = i0 - 3 + t;
            Wn[t] = (r >= 0) ? b2f(al[r * 256 + d]) : 0.f;
        }
        const int qmax = i0 + 15;
        for (int q0 = 0; q0 <= qmax; q0 += 4) {
            float hv[4];
#pragma unroll
            for (int idx = 0; idx < 4; idx++) hv[idx] = hx[(q0 + idx) * 256 + d];
#pragma unroll
            for (int idx = 0; idx < 4; idx++)
#pragma unroll
                for (int ii = 0; ii < 16; ii++)
                    acc[ii] += hv[idx] * Wn[ii + 3 - idx];
            if (q0 + 4 <= qmax) {
#pragma unroll
                for (int t = 18; t >= 4; t--) Wn[t] = Wn[t - 4];
#pragma unroll
                for (int t = 0; t < 4; t++) {
                    int r = i0 - q0 - 7 + t;
                    Wn[t] = (r >= 0) ? b2f(al[r * 256 + d]) : 0.f;
                }
            }
        }
#pragma unroll
        for (int ii = 0; ii < 16; ii++) {
            int i = i0 + ii;
            size_t idx = (size_t)(i * S_DIM + j) * 256 + d;
            float wv  = b2f(Wb[idx]);
            float x0v = b2f(X0[idx]);
            float y = acc[ii] * (1.0f / 256.0f) + wv * fb;
            Gout[idx] = f2b(y * x0v);
        }
    }
}

// ---------------------------------------------------------------------------
extern "C" void kernel_launch(void* const* d_in, const int* in_sizes, int n_in,
                              void* d_out, int out_size, void* d_ws, size_t ws_size,
                              hipStream_t stream)
{
    const void* x     = d_in[0];
    const void* in_w  = d_in[1];
    const void* in_b  = d_in[2];
    const void* out_w = d_in[3];
    const void* out_b_= d_in[4];
    const void* sf_w  = d_in[5];
    const void* sf_b  = d_in[6];
    const void* freq  = d_in[7];
    const void* xw0 = d_in[8];  const void* xb0 = d_in[9];
    const void* xw1 = d_in[10]; const void* xb1 = d_in[11];
    const void* xw2 = d_in[12]; const void* xb2 = d_in[13];
    const void* xw3 = d_in[14];
    const void* yw0 = d_in[15]; const void* yb0 = d_in[16];
    const void* yw1 = d_in[17]; const void* yb1 = d_in[18];
    const void* yw2 = d_in[19]; const void* yb2 = d_in[20];
    const void* yw3 = d_in[21];
    const void* fbias = d_in[22];

    // Workspace layout (~42.7 MB). A_b and G_b overlay dead parts of u_b.
    char* ws = (char*)d_ws;
    unsigned short* u_b  = (unsigned short*)(ws + 0);          // 25165824 B
    unsigned short* A_b  = (unsigned short*)(ws + 0);          //  8388608 B (alias, u dead)
    unsigned short* G_b  = (unsigned short*)(ws + 8388608);    //  8388608 B (alias, u dead)
    unsigned short* Wb_b = (unsigned short*)(ws + 25165824);   //  8388608 B
    unsigned short* X0_b = (unsigned short*)(ws + 33554432);   //  8388608 B
    float* hx            = (float*)(ws + 41943040);            //   131072 B
    float* hy            = (float*)(ws + 42074112);            //   131072 B
    unsigned short* tin  = (unsigned short*)(ws + 42205184);   //   393216 B
    unsigned short* tout = (unsigned short*)(ws + 42598400);   //   131072 B
    int* flag            = (int*)(ws + 42729472);              //       16 B
    // end: 42729488 bytes

    sniff_dtype<<<1, 256, 0, stream>>>((const unsigned short*)x, flag);
    transpose_any<<<dim3((256 * 768 + 255) / 256), 256, 0, stream>>>(in_w, tin, 256, 768, flag);
    transpose_any<<<dim3((256 * 256 + 255) / 256), 256, 0, stream>>>(out_w, tout, 256, 256, flag);
    filter_mlp<<<dim3(S_DIM), 256, 0, stream>>>(freq, xw0, xb0, xw1, xb1, xw2, xb2, xw3, hx, flag);
    filter_mlp<<<dim3(S_DIM), 256, 0, stream>>>(freq, yw0, yb0, yw1, yb1, yw2, yb2, yw3, hy, flag);

    for (int b = 0; b < B_DIM; b++) {
        size_t xoff = (size_t)b * L_DIM * 256;

        gemm_bt<<<dim3(128, 6), 256, 0, stream>>>(
            x, xoff, /*a_ext=*/1, tin, in_b, /*bias_ext=*/1,
            u_b, 0, /*c_ext=*/0, L_DIM, 768, 256, flag);
        conv3_gate<<<dim3(S_DIM, 4), 256, 0, stream>>>(u_b, sf_w, sf_b, Wb_b, X0_b, flag);
        conv_j<<<dim3(S_DIM, 4), 256, 0, stream>>>(Wb_b, hy, A_b);
        conv_i<<<dim3(S_DIM, 4), 256, 0, stream>>>(A_b, hx, Wb_b, X0_b, fbias, G_b, flag);
        gemm_bt<<<dim3(128, 2), 256, 0, stream>>>(
            G_b, 0, /*a_ext=*/0, tout, out_b_, /*bias_ext=*/1,
            d_out, xoff, /*c_ext=*/1, L_DIM, 256, 256, flag);
    }
}

// Round 5
// 711.571 us; speedup vs baseline: 6.7393x; 1.2931x over previous
//
#include <hip/hip_runtime.h>
#include <hip/hip_bf16.h>

#define S_DIM 128
#define B_DIM 4
#define L_DIM (S_DIM * S_DIM)   // 16384 per batch

typedef __bf16 bf16x8 __attribute__((ext_vector_type(8)));
typedef float f32x4 __attribute__((ext_vector_type(4)));

__device__ __forceinline__ float b2f(unsigned short u) {
    union { unsigned int i; float f; } v;
    v.i = ((unsigned int)u) << 16;
    return v.f;
}
__device__ __forceinline__ unsigned short f2b(float f) {
    union { float f; unsigned int i; } v;
    v.f = f;
    unsigned int x = v.i;
    return (unsigned short)((x + 0x7FFFu + ((x >> 16) & 1u)) >> 16);
}
__device__ __forceinline__ float ldx(const void* p, size_t i, int f32) {
    return f32 ? ((const float*)p)[i] : b2f(((const unsigned short*)p)[i]);
}

// ---------------------------------------------------------------------------
__global__ __launch_bounds__(256) void sniff_dtype(const unsigned short* __restrict__ x,
                                                   int* __restrict__ flag) {
    __shared__ int cnt;
    if (threadIdx.x == 0) cnt = 0;
    __syncthreads();
    int c = 0;
    for (int i = threadIdx.x; i < 32768; i += 256) {
        unsigned int e = (x[i] >> 7) & 0xFFu;
        if (e >= 0x91u) c++;
    }
    atomicAdd(&cnt, c);
    __syncthreads();
    if (threadIdx.x == 0) flag[0] = (cnt > 64) ? 1 : 0;
}

// ---------------------------------------------------------------------------
__global__ void transpose_any(const void* __restrict__ src,
                              unsigned short* __restrict__ dst, int R, int C,
                              const int* __restrict__ flag) {
    const int f = flag[0];
    int idx = blockIdx.x * 256 + threadIdx.x;
    if (idx >= R * C) return;
    int r = idx / C, c = idx - r * C;
    dst[c * R + r] = f2b(ldx(src, idx, f));
}

// ---------------------------------------------------------------------------
// Implicit filter MLP: one block per s. out [s][d] f32 (includes decay).
// ---------------------------------------------------------------------------
__global__ __launch_bounds__(256) void filter_mlp(
    const void* __restrict__ freq,
    const void* __restrict__ w0, const void* __restrict__ b0,
    const void* __restrict__ w1, const void* __restrict__ b1,
    const void* __restrict__ w2, const void* __restrict__ b2,
    const void* __restrict__ w3,
    float* __restrict__ out, const int* __restrict__ flag)
{
    __shared__ float hs[64], gs[64];
    const int f32f = flag[0];
    const int s   = blockIdx.x;
    const int tid = threadIdx.x;
    const float t = (float)s / (float)(S_DIM - 1);
    const float ang = 1e-4f * 2.0f * 3.14159265358979323846f * ((float)s / (float)S_DIM);
    const float z0 = t, z1 = cosf(ang), z2 = -sinf(ang);

    if (tid < 64) {
        float fr = ldx(freq, tid, f32f);
        float a = z0 * ldx(w0, 0 * 64 + tid, f32f) + z1 * ldx(w0, 1 * 64 + tid, f32f) +
                  z2 * ldx(w0, 2 * 64 + tid, f32f) + ldx(b0, tid, f32f);
        hs[tid] = sinf(fr * a);
    }
    __syncthreads();
    if (tid < 64) {
        float fr = ldx(freq, tid, f32f);
        float a = ldx(b1, tid, f32f);
        for (int e = 0; e < 64; e++) a += hs[e] * ldx(w1, e * 64 + tid, f32f);
        gs[tid] = sinf(fr * a);
    }
    __syncthreads();
    if (tid < 64) {
        float fr = ldx(freq, tid, f32f);
        float a = ldx(b2, tid, f32f);
        for (int e = 0; e < 64; e++) a += gs[e] * ldx(w2, e * 64 + tid, f32f);
        hs[tid] = sinf(fr * a);
    }
    __syncthreads();
    {
        const float min_d = -3.0701134573253943f;   // ln(0.01)/1.5
        const float max_d = -15.350567286626971f;   // ln(0.01)/0.3
        float a = 0.f;
        for (int e = 0; e < 64; e++) a += hs[e] * ldx(w3, e * 256 + tid, f32f);
        float delta = min_d + (max_d - min_d) * ((float)tid / 255.0f);
        float dec = expf(-t * fabsf(delta));
        out[s * 256 + tid] = a * dec;
    }
}

// ---------------------------------------------------------------------------
// GEMM: C[M][N] = A[M][K] * BT[N][K]^T + bias[N].
// ---------------------------------------------------------------------------
__global__ __launch_bounds__(256) void gemm_bt(
    const void* __restrict__ A, size_t a_off, int a_ext,
    const unsigned short* __restrict__ BT,
    const void* __restrict__ bias, int bias_ext,
    void* __restrict__ C, size_t c_off, int c_ext,
    int M, int N, int K, const int* __restrict__ flag)
{
    __shared__ unsigned short As[128 * 40];  // pad 32 -> 40
    __shared__ unsigned short Bs[128 * 40];

    const int f     = flag[0];
    const int a_f32 = a_ext && f;
    const int b_f32 = bias_ext && f;
    const int c_f32 = c_ext && f;

    const int tid  = threadIdx.x;
    const int m0   = blockIdx.x * 128;
    const int n0   = blockIdx.y * 128;
    const int wid  = tid >> 6;
    const int lane = tid & 63;
    const int lrow = lane & 15;
    const int quad = lane >> 4;
    const int wr   = wid >> 1, wc = wid & 1;

    f32x4 acc[4][4];
#pragma unroll
    for (int a = 0; a < 4; a++)
#pragma unroll
        for (int b = 0; b < 4; b++)
#pragma unroll
            for (int r = 0; r < 4; r++) acc[a][b][r] = 0.0f;

    for (int kc = 0; kc < K; kc += 32) {
#pragma unroll
        for (int h = 0; h < 2; h++) {
            int c    = tid + h * 256;
            int row  = c >> 2;
            int col8 = (c & 3) * 8;
            size_t aidx = a_off + (size_t)(m0 + row) * K + kc + col8;
            if (a_f32) {
                const float4* ga = (const float4*)((const float*)A + aidx);
                float4 p0 = ga[0], p1 = ga[1];
                uint4 w;
                w.x = (unsigned int)f2b(p0.x) | ((unsigned int)f2b(p0.y) << 16);
                w.y = (unsigned int)f2b(p0.z) | ((unsigned int)f2b(p0.w) << 16);
                w.z = (unsigned int)f2b(p1.x) | ((unsigned int)f2b(p1.y) << 16);
                w.w = (unsigned int)f2b(p1.z) | ((unsigned int)f2b(p1.w) << 16);
                *(uint4*)(&As[row * 40 + col8]) = w;
            } else {
                *(uint4*)(&As[row * 40 + col8]) =
                    *(const uint4*)((const unsigned short*)A + aidx);
            }
            *(uint4*)(&Bs[row * 40 + col8]) =
                *(const uint4*)(BT + (size_t)(n0 + row) * K + kc + col8);
        }
        __syncthreads();

        bf16x8 af[4], bfr[4];
#pragma unroll
        for (int fm = 0; fm < 4; fm++)
            af[fm] = *(const bf16x8*)(&As[(wr * 64 + fm * 16 + lrow) * 40 + quad * 8]);
#pragma unroll
        for (int fn = 0; fn < 4; fn++)
            bfr[fn] = *(const bf16x8*)(&Bs[(wc * 64 + fn * 16 + lrow) * 40 + quad * 8]);
#pragma unroll
        for (int fm = 0; fm < 4; fm++)
#pragma unroll
            for (int fn = 0; fn < 4; fn++)
                acc[fm][fn] = __builtin_amdgcn_mfma_f32_16x16x32_bf16(
                    af[fm], bfr[fn], acc[fm][fn], 0, 0, 0);
        __syncthreads();
    }

#pragma unroll
    for (int fm = 0; fm < 4; fm++) {
#pragma unroll
        for (int fn = 0; fn < 4; fn++) {
            int gcol = n0 + wc * 64 + fn * 16 + lrow;
            float bv = ldx(bias, gcol, b_f32);
#pragma unroll
            for (int r = 0; r < 4; r++) {
                int grow = m0 + wr * 64 + fm * 16 + quad * 4 + r;
                size_t cidx = c_off + (size_t)grow * N + gcol;
                float val = acc[fm][fn][r] + bv;
                if (c_f32) ((float*)C)[cidx] = val;
                else       ((unsigned short*)C)[cidx] = f2b(val);
            }
        }
    }
}

// ---------------------------------------------------------------------------
// Depthwise 3x3 (taps -2,-1,0) + gate. Batched via blockIdx.z (stride u_zs/o_zs
// elements). Grid (S, 4, nb). Software-prefetch of next column.
// ---------------------------------------------------------------------------
__global__ __launch_bounds__(256) void conv3_gate(
    const unsigned short* __restrict__ U, size_t u_zs,
    const void* __restrict__ sfw, const void* __restrict__ sfb,
    unsigned short* __restrict__ Wb, unsigned short* __restrict__ X0, size_t o_zs,
    const int* __restrict__ flag)
{
    const int f32f = flag[0];
    const int i   = blockIdx.x;
    const int j0  = blockIdx.y * 32;
    const int tid = threadIdx.x;
    const unsigned short* Ub = U + (size_t)blockIdx.z * u_zs;
    unsigned short* Wbb = Wb + (size_t)blockIdx.z * o_zs;
    unsigned short* X0b = X0 + (size_t)blockIdx.z * o_zs;

    float wgt[3][3][3], bias[3];
#pragma unroll
    for (int cc = 0; cc < 3; cc++) {
        int ch = cc * 256 + tid;
        bias[cc] = ldx(sfb, ch, f32f);
#pragma unroll
        for (int ki = 0; ki < 3; ki++)
#pragma unroll
            for (int kj = 0; kj < 3; kj++)
                wgt[cc][ki][kj] = ldx(sfw, ch * 9 + ki * 3 + kj, f32f);
    }

    float colA[3][3], colB[3][3], cur[3][3];
    // load column col into dst (zeros for col<0 / row<0)
#define LOAD_COL(dst, col)                                                        \
    {                                                                             \
        _Pragma("unroll")                                                         \
        for (int ki = 0; ki < 3; ki++) {                                          \
            int row = i + ki - 2;                                                 \
            bool ok = (row >= 0) && ((col) >= 0);                                 \
            _Pragma("unroll")                                                     \
            for (int cc = 0; cc < 3; cc++)                                        \
                dst[cc][ki] = ok ? b2f(Ub[(size_t)(row * S_DIM + (col)) * 768 +   \
                                          cc * 256 + tid]) : 0.f;                 \
        }                                                                         \
    }

    LOAD_COL(colA, j0 - 2)
    LOAD_COL(colB, j0 - 1)
    LOAD_COL(cur, j0)

    for (int j = j0; j < j0 + 32; j++) {
        float nxt[3][3];
        int jn = j + 1;
        if (jn < S_DIM) { LOAD_COL(nxt, jn) }
        else {
#pragma unroll
            for (int ki = 0; ki < 3; ki++)
#pragma unroll
                for (int cc = 0; cc < 3; cc++) nxt[cc][ki] = 0.f;
        }

        float o[3];
#pragma unroll
        for (int cc = 0; cc < 3; cc++) {
            float a = bias[cc];
#pragma unroll
            for (int ki = 0; ki < 3; ki++)
                a += wgt[cc][ki][0] * colA[cc][ki] + wgt[cc][ki][1] * colB[cc][ki] +
                     wgt[cc][ki][2] * cur[cc][ki];
            o[cc] = a;
        }
        size_t oidx = (size_t)(i * S_DIM + j) * 256 + tid;
        X0b[oidx] = f2b(o[0]);
        Wbb[oidx] = f2b(o[2] * o[1]);  // v * x1

#pragma unroll
        for (int cc = 0; cc < 3; cc++)
#pragma unroll
            for (int ki = 0; ki < 3; ki++) {
                colA[cc][ki] = colB[cc][ki];
                colB[cc][ki] = cur[cc][ki];
                cur[cc][ki]  = nxt[cc][ki];
            }
    }
#undef LOAD_COL
}

// ---------------------------------------------------------------------------
// Causal conv along j. Grid (S, 4, nb): block h does balanced tile pair {h,7-h}.
// ---------------------------------------------------------------------------
__global__ __launch_bounds__(256) void conv_j(
    const unsigned short* __restrict__ Wb, size_t zs,
    const float* __restrict__ hy,
    unsigned short* __restrict__ Aout)
{
    __shared__ unsigned short wl[S_DIM * 256];  // 64 KB, [j][d]
    const int i = blockIdx.x;
    const int h = blockIdx.y;
    const int tid = threadIdx.x;
    const size_t zoff = (size_t)blockIdx.z * zs;
    const size_t sbase = zoff + (size_t)(i * S_DIM) * 256;

    const uint4* gsrc = (const uint4*)(Wb + sbase);
    for (int c = tid; c < 4096; c += 256) ((uint4*)wl)[c] = gsrc[c];
    __syncthreads();

    const int d = tid;
    for (int pick = 0; pick < 2; pick++) {
        const int jt = pick ? (7 - h) : h;
        const int j0 = jt * 16;
        float acc[16];
#pragma unroll
        for (int jj = 0; jj < 16; jj++) acc[jj] = 0.f;

        float Wn[19];
#pragma unroll
        for (int t = 0; t < 19; t++) {
            int r = j0 - 3 + t;
            Wn[t] = (r >= 0) ? b2f(wl[r * 256 + d]) : 0.f;
        }
        const int qmax = j0 + 15;
        for (int q0 = 0; q0 <= qmax; q0 += 4) {
            float hv[4];
#pragma unroll
            for (int idx = 0; idx < 4; idx++) hv[idx] = hy[(q0 + idx) * 256 + d];
#pragma unroll
            for (int idx = 0; idx < 4; idx++)
#pragma unroll
                for (int jj = 0; jj < 16; jj++)
                    acc[jj] += hv[idx] * Wn[jj + 3 - idx];
            if (q0 + 4 <= qmax) {
#pragma unroll
                for (int t = 18; t >= 4; t--) Wn[t] = Wn[t - 4];
#pragma unroll
                for (int t = 0; t < 4; t++) {
                    int r = j0 - q0 - 7 + t;
                    Wn[t] = (r >= 0) ? b2f(wl[r * 256 + d]) : 0.f;
                }
            }
        }
#pragma unroll
        for (int jj = 0; jj < 16; jj++)
            Aout[sbase + (size_t)(j0 + jj) * 256 + d] = f2b(acc[jj]);
    }
}

// ---------------------------------------------------------------------------
// Causal conv along i + epilogue. Grid (S, 4, nb).
// ---------------------------------------------------------------------------
__global__ __launch_bounds__(256) void conv_i(
    const unsigned short* __restrict__ Ain, size_t zs,
    const float* __restrict__ hx,
    const unsigned short* __restrict__ Wb,
    const unsigned short* __restrict__ X0,
    const void* __restrict__ fbias,
    unsigned short* __restrict__ Gout,
    const int* __restrict__ flag)
{
    __shared__ unsigned short al[S_DIM * 256];  // [i][d]
    const int f32f = flag[0];
    const int j = blockIdx.x;
    const int h = blockIdx.y;
    const int tid = threadIdx.x;
    const size_t zoff = (size_t)blockIdx.z * zs;

    for (int c = tid; c < 4096; c += 256) {
        int row = c >> 5;
        int off = c & 31;
        const uint4* gsrc = (const uint4*)(Ain + zoff + (size_t)(row * S_DIM + j) * 256) + off;
        ((uint4*)al)[c] = *gsrc;
    }
    __syncthreads();

    const int d = tid;
    const float fb = ldx(fbias, d, f32f);
    for (int pick = 0; pick < 2; pick++) {
        const int it = pick ? (7 - h) : h;
        const int i0 = it * 16;
        float acc[16];
#pragma unroll
        for (int ii = 0; ii < 16; ii++) acc[ii] = 0.f;

        float Wn[19];
#pragma unroll
        for (int t = 0; t < 19; t++) {
            int r = i0 - 3 + t;
            Wn[t] = (r >= 0) ? b2f(al[r * 256 + d]) : 0.f;
        }
        const int qmax = i0 + 15;
        for (int q0 = 0; q0 <= qmax; q0 += 4) {
            float hv[4];
#pragma unroll
            for (int idx = 0; idx < 4; idx++) hv[idx] = hx[(q0 + idx) * 256 + d];
#pragma unroll
            for (int idx = 0; idx < 4; idx++)
#pragma unroll
                for (int ii = 0; ii < 16; ii++)
                    acc[ii] += hv[idx] * Wn[ii + 3 - idx];
            if (q0 + 4 <= qmax) {
#pragma unroll
                for (int t = 18; t >= 4; t--) Wn[t] = Wn[t - 4];
#pragma unroll
                for (int t = 0; t < 4; t++) {
                    int r = i0 - q0 - 7 + t;
                    Wn[t] = (r >= 0) ? b2f(al[r * 256 + d]) : 0.f;
                }
            }
        }
#pragma unroll
        for (int ii = 0; ii < 16; ii++) {
            int i = i0 + ii;
            size_t idx = zoff + (size_t)(i * S_DIM + j) * 256 + d;
            float wv  = b2f(Wb[idx]);
            float x0v = b2f(X0[idx]);
            float y = acc[ii] * (1.0f / 256.0f) + wv * fb;
            Gout[idx] = f2b(y * x0v);
        }
    }
}

// ---------------------------------------------------------------------------
extern "C" void kernel_launch(void* const* d_in, const int* in_sizes, int n_in,
                              void* d_out, int out_size, void* d_ws, size_t ws_size,
                              hipStream_t stream)
{
    const void* x     = d_in[0];
    const void* in_w  = d_in[1];
    const void* in_b  = d_in[2];
    const void* out_w = d_in[3];
    const void* out_b_= d_in[4];
    const void* sf_w  = d_in[5];
    const void* sf_b  = d_in[6];
    const void* freq  = d_in[7];
    const void* xw0 = d_in[8];  const void* xb0 = d_in[9];
    const void* xw1 = d_in[10]; const void* xb1 = d_in[11];
    const void* xw2 = d_in[12]; const void* xb2 = d_in[13];
    const void* xw3 = d_in[14];
    const void* yw0 = d_in[15]; const void* yb0 = d_in[16];
    const void* yw1 = d_in[17]; const void* yb1 = d_in[18];
    const void* yw2 = d_in[19]; const void* yb2 = d_in[20];
    const void* yw3 = d_in[21];
    const void* fbias = d_in[22];

    char* ws = (char*)d_ws;
    const size_t UZ  = (size_t)L_DIM * 768;   // elements per batch, u
    const size_t OZ  = (size_t)L_DIM * 256;   // elements per batch, 256-ch bufs

    // Fused (all-batch) layout: 168,558,608 B. Fallback per-batch: 42,729,488 B.
    const size_t need_fused = 168558608;
    bool fused = (ws_size >= need_fused);

    if (fused) {
        unsigned short* u_f  = (unsigned short*)(ws + 0);           // 100663296 B
        unsigned short* A_f  = (unsigned short*)(ws + 0);           //  33554432 B (alias)
        unsigned short* G_f  = (unsigned short*)(ws + 33554432);    //  33554432 B (alias)
        unsigned short* Wb_f = (unsigned short*)(ws + 100663296);   //  33554432 B
        unsigned short* X0_f = (unsigned short*)(ws + 134217728);   //  33554432 B
        float* hx            = (float*)(ws + 167772160);
        float* hy            = (float*)(ws + 167903232);
        unsigned short* tin  = (unsigned short*)(ws + 168034304);
        unsigned short* tout = (unsigned short*)(ws + 168427520);
        int* flag            = (int*)(ws + 168558592);

        sniff_dtype<<<1, 256, 0, stream>>>((const unsigned short*)x, flag);
        transpose_any<<<dim3(768), 256, 0, stream>>>(in_w, tin, 256, 768, flag);
        transpose_any<<<dim3(256), 256, 0, stream>>>(out_w, tout, 256, 256, flag);
        filter_mlp<<<dim3(S_DIM), 256, 0, stream>>>(freq, xw0, xb0, xw1, xb1, xw2, xb2, xw3, hx, flag);
        filter_mlp<<<dim3(S_DIM), 256, 0, stream>>>(freq, yw0, yb0, yw1, yb1, yw2, yb2, yw3, hy, flag);

        gemm_bt<<<dim3(512, 6), 256, 0, stream>>>(
            x, 0, 1, tin, in_b, 1, u_f, 0, 0, B_DIM * L_DIM, 768, 256, flag);
        conv3_gate<<<dim3(S_DIM, 4, B_DIM), 256, 0, stream>>>(
            u_f, UZ, sf_w, sf_b, Wb_f, X0_f, OZ, flag);
        conv_j<<<dim3(S_DIM, 4, B_DIM), 256, 0, stream>>>(Wb_f, OZ, hy, A_f);
        conv_i<<<dim3(S_DIM, 4, B_DIM), 256, 0, stream>>>(
            A_f, OZ, hx, Wb_f, X0_f, fbias, G_f, flag);
        gemm_bt<<<dim3(512, 2), 256, 0, stream>>>(
            G_f, 0, 0, tout, out_b_, 1, d_out, 0, 1, B_DIM * L_DIM, 256, 256, flag);
    } else {
        unsigned short* u_b  = (unsigned short*)(ws + 0);          // 25165824 B
        unsigned short* A_b  = (unsigned short*)(ws + 0);          // alias
        unsigned short* G_b  = (unsigned short*)(ws + 8388608);    // alias
        unsigned short* Wb_b = (unsigned short*)(ws + 25165824);
        unsigned short* X0_b = (unsigned short*)(ws + 33554432);
        float* hx            = (float*)(ws + 41943040);
        float* hy            = (float*)(ws + 42074112);
        unsigned short* tin  = (unsigned short*)(ws + 42205184);
        unsigned short* tout = (unsigned short*)(ws + 42598400);
        int* flag            = (int*)(ws + 42729472);

        sniff_dtype<<<1, 256, 0, stream>>>((const unsigned short*)x, flag);
        transpose_any<<<dim3(768), 256, 0, stream>>>(in_w, tin, 256, 768, flag);
        transpose_any<<<dim3(256), 256, 0, stream>>>(out_w, tout, 256, 256, flag);
        filter_mlp<<<dim3(S_DIM), 256, 0, stream>>>(freq, xw0, xb0, xw1, xb1, xw2, xb2, xw3, hx, flag);
        filter_mlp<<<dim3(S_DIM), 256, 0, stream>>>(freq, yw0, yb0, yw1, yb1, yw2, yb2, yw3, hy, flag);

        for (int b = 0; b < B_DIM; b++) {
            size_t xoff = (size_t)b * OZ;
            gemm_bt<<<dim3(128, 6), 256, 0, stream>>>(
                x, xoff, 1, tin, in_b, 1, u_b, 0, 0, L_DIM, 768, 256, flag);
            conv3_gate<<<dim3(S_DIM, 4, 1), 256, 0, stream>>>(
                u_b, 0, sf_w, sf_b, Wb_b, X0_b, 0, flag);
            conv_j<<<dim3(S_DIM, 4, 1), 256, 0, stream>>>(Wb_b, 0, hy, A_b);
            conv_i<<<dim3(S_DIM, 4, 1), 256, 0, stream>>>(
                A_b, 0, hx, Wb_b, X0_b, fbias, G_b, flag);
            gemm_bt<<<dim3(128, 2), 256, 0, stream>>>(
                G_b, 0, 0, tout, out_b_, 1, d_out, xoff, 1, L_DIM, 256, 256, flag);
        }
    }
}